// Round 7
// baseline (620.733 us; speedup 1.0000x reference)
//
#include <hip/hip_runtime.h>
#include <hip/hip_fp16.h>

#define NBLK 1024        // blocks for edge-streaming passes
#define BTHREADS 256
#define BB 10            // bucket bits: 1024 nodes per bucket
#define BSZ (1 << BB)
#define BMASK (BSZ - 1)
#define MAXNB 1024       // max buckets supported (N <= 1,048,576 at BB=10)
#define GTHREADS 512     // gather/accumulate kernels
#define ILP 8

// ---------------- helpers ----------------
__device__ __forceinline__ int detect64(const int* __restrict__ ei) {
    return (ei[1] | ei[3] | ei[5] | ei[7] | ei[9] | ei[11] | ei[13] | ei[15]) == 0;
}
__device__ __forceinline__ int load_src(const int* __restrict__ ei, int e, int is64) {
    return is64 ? ei[2 * (size_t)e] : ei[(size_t)e];
}
__device__ __forceinline__ int load_dst(const int* __restrict__ ei, int E, int e, int is64) {
    return is64 ? ei[2 * ((size_t)E + e)] : ei[(size_t)E + e];
}
__device__ __forceinline__ unsigned int h2u(__half2 h) {
    union { __half2 h; unsigned int u; } c; c.h = h; return c.u;
}
__device__ __forceinline__ __half2 u2h(unsigned int u) {
    union { __half2 h; unsigned int u; } c; c.u = u; return c.h;
}

// Pass 1: per-block histogram of dst buckets. No global atomics.
__global__ __launch_bounds__(BTHREADS) void pass1_hist(
    const int* __restrict__ ei, int E, int NB, unsigned int* __restrict__ off) {
    __shared__ unsigned int hist[MAXNB];
    int t = threadIdx.x, blk = blockIdx.x;
    for (int u = t; u < MAXNB; u += BTHREADS) hist[u] = 0;
    __syncthreads();
    int is64 = detect64(ei);
    int chunk = (E + NBLK - 1) / NBLK;
    int lo = blk * chunk;
    int hi = lo + chunk; if (hi > E) hi = E;
    for (int e = lo + t; e < hi; e += BTHREADS) {
        int d = load_dst(ei, E, e, is64);
        atomicAdd(&hist[d >> BB], 1u);
    }
    __syncthreads();
    for (int u = t; u < NB; u += BTHREADS) off[(size_t)u * NBLK + blk] = hist[u];
}

// Scan A: per bucket, exclusive scan over the 1024 per-block counts.
__global__ __launch_bounds__(BTHREADS) void scan_blocks(
    unsigned int* __restrict__ off, unsigned int* __restrict__ btot) {
    __shared__ unsigned int s[BTHREADS];
    int b = blockIdx.x, t = threadIdx.x;
    unsigned int* row = off + (size_t)b * NBLK;
    unsigned int v0 = row[4 * t], v1 = row[4 * t + 1], v2 = row[4 * t + 2], v3 = row[4 * t + 3];
    unsigned int sum = v0 + v1 + v2 + v3;
    s[t] = sum;
    __syncthreads();
    for (int o = 1; o < BTHREADS; o <<= 1) {
        unsigned int x = (t >= o) ? s[t - o] : 0;
        __syncthreads();
        s[t] += x;
        __syncthreads();
    }
    unsigned int base = t ? s[t - 1] : 0;
    row[4 * t] = base;
    row[4 * t + 1] = base + v0;
    row[4 * t + 2] = base + v0 + v1;
    row[4 * t + 3] = base + v0 + v1 + v2;
    if (t == BTHREADS - 1) btot[b] = s[BTHREADS - 1];
}

// Scan B: exclusive scan over bucket totals (NB <= 1024, 4 per thread).
__global__ __launch_bounds__(BTHREADS) void scan_buckets(
    const unsigned int* __restrict__ btot, unsigned int* __restrict__ bbase, int NB) {
    __shared__ unsigned int s[BTHREADS];
    int t = threadIdx.x;
    unsigned int v[4];
#pragma unroll
    for (int j = 0; j < 4; ++j) {
        int idx = 4 * t + j;
        v[j] = (idx < NB) ? btot[idx] : 0;
    }
    unsigned int sum = v[0] + v[1] + v[2] + v[3];
    s[t] = sum;
    __syncthreads();
    for (int o = 1; o < BTHREADS; o <<= 1) {
        unsigned int x = (t >= o) ? s[t - o] : 0;
        __syncthreads();
        s[t] += x;
        __syncthreads();
    }
    unsigned int base = t ? s[t - 1] : 0;
    unsigned int run = base;
#pragma unroll
    for (int j = 0; j < 4; ++j) {
        int idx = 4 * t + j;
        if (idx < NB) bbase[idx] = run;
        run += v[j];
    }
}

// Pass 2: scatter packed records (src<<BB | dstlow) into bucket-contiguous ebin.
__global__ __launch_bounds__(BTHREADS) void pass2_scatter(
    const int* __restrict__ ei, int E, int NB,
    const unsigned int* __restrict__ off, const unsigned int* __restrict__ bbase,
    unsigned int* __restrict__ ebin) {
    __shared__ unsigned int cur[MAXNB];
    int t = threadIdx.x, blk = blockIdx.x;
    for (int u = t; u < NB; u += BTHREADS)
        cur[u] = bbase[u] + off[(size_t)u * NBLK + blk];
    __syncthreads();
    int is64 = detect64(ei);
    int chunk = (E + NBLK - 1) / NBLK;
    int lo = blk * chunk;
    int hi = lo + chunk; if (hi > E) hi = E;
    for (int e = lo + t; e < hi; e += BTHREADS) {
        int s = load_src(ei, e, is64);
        int d = load_dst(ei, E, e, is64);
        unsigned int pos = atomicAdd(&cur[d >> BB], 1u);
        ebin[pos] = ((unsigned int)s << BB) | (unsigned int)(d & BMASK);
    }
}

// Per bucket: degree histogram in LDS -> dinv (f32), xs = half4(x * dinv) (uint2).
__global__ __launch_bounds__(GTHREADS) void deg_prep(
    const unsigned int* __restrict__ ebin, const unsigned int* __restrict__ bbase,
    const unsigned int* __restrict__ btot, const float4* __restrict__ x,
    float* __restrict__ dinv, uint2* __restrict__ xs, int N) {
    __shared__ unsigned int dcnt[BSZ];
    int b = blockIdx.x, t = threadIdx.x;
    for (int j = t; j < BSZ; j += GTHREADS) dcnt[j] = 0;
    __syncthreads();
    unsigned int base = bbase[b];
    int cnt = (int)btot[b];
    for (int i = t; i < cnt; i += GTHREADS)
        atomicAdd(&dcnt[ebin[base + i] & BMASK], 1u);
    __syncthreads();
    int g0 = b << BB;
    int nn = N - g0; if (nn > BSZ) nn = BSZ;
    for (int j = t; j < nn; j += GTHREADS) {
        int g = g0 + j;
        float di = rsqrtf((float)(dcnt[j] + 1u));
        dinv[g] = di;
        float4 v = x[g];
        uint2 p;
        p.x = h2u(__halves2half2(__float2half_rn(v.x * di), __float2half_rn(v.y * di)));
        p.y = h2u(__halves2half2(__float2half_rn(v.z * di), __float2half_rn(v.w * di)));
        xs[g] = p;
    }
}

// Layer-1 gather/accumulate: low-VGPR, high-occupancy, ILP-deep batched gathers.
__global__ __launch_bounds__(GTHREADS, 8) void l1_gather(
    const unsigned int* __restrict__ ebin, const unsigned int* __restrict__ bbase,
    const unsigned int* __restrict__ btot,
    const uint2* __restrict__ xs, float4* __restrict__ agg, int N) {
    __shared__ float acc[BSZ][4];   // 16 KB
    int b = blockIdx.x, t = threadIdx.x;
    {
        float* p = &acc[0][0];
        for (int j = t; j < BSZ * 4; j += GTHREADS) p[j] = 0.0f;
    }
    __syncthreads();
    unsigned int base = bbase[b];
    int cnt = (int)btot[b];
    for (int i0 = ILP * t; i0 < cnt; i0 += ILP * GTHREADS) {
        int m = cnt - i0; if (m > ILP) m = ILP;
        unsigned int rec[ILP];
        uint2 raw[ILP];
#pragma unroll
        for (int j = 0; j < ILP; ++j) if (j < m) rec[j] = ebin[base + i0 + j];
#pragma unroll
        for (int j = 0; j < ILP; ++j) if (j < m) raw[j] = xs[rec[j] >> BB];
#pragma unroll
        for (int j = 0; j < ILP; ++j) if (j < m) {
            int d = rec[j] & BMASK;
            __half2 h01 = u2h(raw[j].x), h23 = u2h(raw[j].y);
            atomicAdd(&acc[d][0], __half2float(__low2half(h01)));
            atomicAdd(&acc[d][1], __half2float(__high2half(h01)));
            atomicAdd(&acc[d][2], __half2float(__low2half(h23)));
            atomicAdd(&acc[d][3], __half2float(__high2half(h23)));
        }
    }
    __syncthreads();
    int g0 = b << BB;
    int nn = N - g0; if (nn > BSZ) nn = BSZ;
    for (int j = t; j < nn; j += GTHREADS)
        agg[g0 + j] = make_float4(acc[j][0], acc[j][1], acc[j][2], acc[j][3]);
}

// Layer-1 MLP epilogue: streaming, register-fat is fine here.
__global__ __launch_bounds__(256) void l1_mlp(
    const float4* __restrict__ agg, const uint2* __restrict__ xs,
    const float* __restrict__ dinv,
    const float* __restrict__ W1, const float* __restrict__ b1,
    const float* __restrict__ W2, unsigned int* __restrict__ ps, int N) {
    __shared__ float sW1[256];
    __shared__ float sb1[64];
    __shared__ float sW2[128];
    int t = threadIdx.x;
    sW1[t] = W1[t];
    if (t < 64) sb1[t] = b1[t];
    if (t < 128) sW2[t] = W2[t];
    __syncthreads();
    int i = blockIdx.x * 256 + t;
    if (i >= N) return;
    float di = dinv[i];
    float4 a = agg[i];
    uint2 raw = xs[i];  // self-loop (quantized, consistent)
    __half2 h01 = u2h(raw.x), h23 = u2h(raw.y);
    float ax = (a.x + __half2float(__low2half(h01))) * di;
    float ay = (a.y + __half2float(__high2half(h01))) * di;
    float az = (a.z + __half2float(__low2half(h23))) * di;
    float aw = (a.w + __half2float(__high2half(h23))) * di;
    float p0 = 0.0f, p1 = 0.0f;
#pragma unroll
    for (int k = 0; k < 64; ++k) {
        float h = fmaf(ax, sW1[k],
                  fmaf(ay, sW1[64 + k],
                  fmaf(az, sW1[128 + k],
                  fmaf(aw, sW1[192 + k], sb1[k]))));
        h = fmaxf(h, 0.0f);
        p0 = fmaf(h, sW2[2 * k + 0], p0);
        p1 = fmaf(h, sW2[2 * k + 1], p1);
    }
    ps[i] = h2u(__halves2half2(__float2half_rn(p0 * di), __float2half_rn(p1 * di)));
}

// Layer 2: gather half2 ps[src] (4 MB table), LDS accumulate, epilogue. ILP-deep.
__global__ __launch_bounds__(GTHREADS, 8) void l2_agg(
    const unsigned int* __restrict__ ebin, const unsigned int* __restrict__ bbase,
    const unsigned int* __restrict__ btot,
    const unsigned int* __restrict__ ps, const float* __restrict__ dinv,
    const float* __restrict__ b2, float2* __restrict__ out, int N) {
    __shared__ float acc[BSZ][2];   // 8 KB
    int b = blockIdx.x, t = threadIdx.x;
    {
        float* p = &acc[0][0];
        for (int j = t; j < BSZ * 2; j += GTHREADS) p[j] = 0.0f;
    }
    __syncthreads();
    unsigned int base = bbase[b];
    int cnt = (int)btot[b];
    for (int i0 = ILP * t; i0 < cnt; i0 += ILP * GTHREADS) {
        int m = cnt - i0; if (m > ILP) m = ILP;
        unsigned int rec[ILP];
        unsigned int raw[ILP];
#pragma unroll
        for (int j = 0; j < ILP; ++j) if (j < m) rec[j] = ebin[base + i0 + j];
#pragma unroll
        for (int j = 0; j < ILP; ++j) if (j < m) raw[j] = ps[rec[j] >> BB];
#pragma unroll
        for (int j = 0; j < ILP; ++j) if (j < m) {
            int d = rec[j] & BMASK;
            __half2 h = u2h(raw[j]);
            atomicAdd(&acc[d][0], __half2float(__low2half(h)));
            atomicAdd(&acc[d][1], __half2float(__high2half(h)));
        }
    }
    __syncthreads();
    int g0 = b << BB;
    int nn = N - g0; if (nn > BSZ) nn = BSZ;
    float c0 = b2[0], c1 = b2[1];
    for (int j = t; j < nn; j += GTHREADS) {
        int g = g0 + j;
        float di = dinv[g];
        __half2 h = u2h(ps[g]);  // self-loop
        float2 r;
        r.x = fmaf(acc[j][0] + __half2float(__low2half(h)), di, c0);
        r.y = fmaf(acc[j][1] + __half2float(__high2half(h)), di, c1);
        out[g] = r;
    }
}

static inline size_t align256(size_t v) { return (v + 255) & ~(size_t)255; }

extern "C" void kernel_launch(void* const* d_in, const int* in_sizes, int n_in,
                              void* d_out, int out_size, void* d_ws, size_t ws_size,
                              hipStream_t stream) {
    const float* x  = (const float*)d_in[0];
    const int*   ei = (const int*)d_in[1];
    const float* W1 = (const float*)d_in[2];
    const float* b1 = (const float*)d_in[3];
    const float* W2 = (const float*)d_in[4];
    const float* b2 = (const float*)d_in[5];

    const int N = in_sizes[0] / 4;
    const int E = in_sizes[1] / 2;
    const int NB = (N + BSZ - 1) >> BB;

    char* ws = (char*)d_ws;
    size_t o = 0;
    unsigned int* ebin  = (unsigned int*)(ws + o); o = align256(o + (size_t)E * 4);
    unsigned int* off   = (unsigned int*)(ws + o); o = align256(o + (size_t)MAXNB * NBLK * 4);
    unsigned int* btot  = (unsigned int*)(ws + o); o = align256(o + (size_t)MAXNB * 4);
    unsigned int* bbase = (unsigned int*)(ws + o); o = align256(o + (size_t)MAXNB * 4);
    float*        dinv  = (float*)(ws + o);        o = align256(o + (size_t)N * 4);
    uint2*        xs    = (uint2*)(ws + o);        o = align256(o + (size_t)N * 8);
    unsigned int* ps    = (unsigned int*)(ws + o); o = align256(o + (size_t)N * 4);
    float4*       agg   = (float4*)(ws + o);       o = align256(o + (size_t)N * 16);

    pass1_hist<<<NBLK, BTHREADS, 0, stream>>>(ei, E, NB, off);
    scan_blocks<<<NB, BTHREADS, 0, stream>>>(off, btot);
    scan_buckets<<<1, BTHREADS, 0, stream>>>(btot, bbase, NB);
    pass2_scatter<<<NBLK, BTHREADS, 0, stream>>>(ei, E, NB, off, bbase, ebin);
    deg_prep<<<NB, GTHREADS, 0, stream>>>(ebin, bbase, btot, (const float4*)x, dinv, xs, N);
    l1_gather<<<NB, GTHREADS, 0, stream>>>(ebin, bbase, btot, xs, agg, N);
    l1_mlp<<<(N + 255) / 256, 256, 0, stream>>>(agg, xs, dinv, W1, b1, W2, ps, N);
    l2_agg<<<NB, GTHREADS, 0, stream>>>(ebin, bbase, btot, ps, dinv, b2, (float2*)d_out, N);
}